// Round 1
// baseline (106.704 us; speedup 1.0000x reference)
//
#include <hip/hip_runtime.h>
#include <math.h>

#define NBOX 4096
#define TILE 32
#define NT (NBOX / TILE)

// Per-box precomputed struct, 16 floats:
// [0..7]  corners: c0x,c0y,c1x,c1y,c2x,c2y,c3x,c3y
// [8..11] axes:    a0x,a0y,a1x,a1y   (a0 = c1-c0, a1 = c3-c0)
// [12..15] self-proj: smin0,smax0,smin1,smax1

__device__ __forceinline__ float rcp_fast(float x) {
    return __builtin_amdgcn_rcpf(x);
}

__device__ __forceinline__ float giou1d(float mn1, float mx1, float mn2, float mx2) {
    float inter = fminf(mx1, mx2) - fmaxf(mn1, mn2);
    inter = fmaxf(inter, 0.0f);
    float uni  = (mx1 - mn1) + (mx2 - mn2) - inter;
    float hull = fmaxf(mx1, mx2) - fminf(mn1, mn2);
    return inter * rcp_fast(uni) - (hull - uni) * rcp_fast(hull);
}

__global__ void precompute_kernel(const float* __restrict__ boxes,
                                  float* __restrict__ bd) {
    int b = blockIdx.x * blockDim.x + threadIdx.x;
    if (b >= NBOX) return;
    float cx = boxes[b * 5 + 0];
    float cy = boxes[b * 5 + 1];
    float hw = boxes[b * 5 + 2] * 0.5f;
    float hh = boxes[b * 5 + 3] * 0.5f;
    float ang = boxes[b * 5 + 4];
    float s, c;
    sincosf(ang, &s, &c);
    // rotated half-extent vectors (match reference einsum exactly):
    // corner = center + ux*(hw*c, -hw*s) + uy*(hh*s, hh*c), (ux,uy) in unit square
    float e0x = hw * c,  e0y = -hw * s;
    float e1x = hh * s,  e1y =  hh * c;
    float c0x = cx - e0x - e1x, c0y = cy - e0y - e1y;
    float c1x = cx + e0x - e1x, c1y = cy + e0y - e1y;
    float c2x = cx + e0x + e1x, c2y = cy + e0y + e1y;
    float c3x = cx - e0x + e1x, c3y = cy - e0y + e1y;
    float a0x = c1x - c0x, a0y = c1y - c0y;
    float a1x = c3x - c0x, a1y = c3y - c0y;
    // self projections
    float p0 = c0x * a0x + c0y * a0y;
    float p1 = c1x * a0x + c1y * a0y;
    float p2 = c2x * a0x + c2y * a0y;
    float p3 = c3x * a0x + c3y * a0y;
    float smin0 = fminf(fminf(p0, p1), fminf(p2, p3));
    float smax0 = fmaxf(fmaxf(p0, p1), fmaxf(p2, p3));
    float q0 = c0x * a1x + c0y * a1y;
    float q1 = c1x * a1x + c1y * a1y;
    float q2 = c2x * a1x + c2y * a1y;
    float q3 = c3x * a1x + c3y * a1y;
    float smin1 = fminf(fminf(q0, q1), fminf(q2, q3));
    float smax1 = fmaxf(fmaxf(q0, q1), fmaxf(q2, q3));

    float4* dst = (float4*)(bd + (size_t)b * 16);
    dst[0] = make_float4(c0x, c0y, c1x, c1y);
    dst[1] = make_float4(c2x, c2y, c3x, c3y);
    dst[2] = make_float4(a0x, a0y, a1x, a1y);
    dst[3] = make_float4(smin0, smax0, smin1, smax1);
}

// Full MGIoU for one (i,j) pair from the two 16-float structs (LDS pointers,
// constant offsets only — no scratch).
__device__ __forceinline__ float mgiou_pair(const float* __restrict__ I,
                                            const float* __restrict__ J) {
    float g;
    {   // gA axis 0: J corners onto I axis0 vs I self-proj
        float ax = I[8], ay = I[9];
        float p0 = fmaf(J[0], ax, J[1] * ay);
        float p1 = fmaf(J[2], ax, J[3] * ay);
        float p2 = fmaf(J[4], ax, J[5] * ay);
        float p3 = fmaf(J[6], ax, J[7] * ay);
        float mn = fminf(fminf(p0, p1), fminf(p2, p3));
        float mx = fmaxf(fmaxf(p0, p1), fmaxf(p2, p3));
        g = giou1d(I[12], I[13], mn, mx);
    }
    {   // gA axis 1
        float ax = I[10], ay = I[11];
        float p0 = fmaf(J[0], ax, J[1] * ay);
        float p1 = fmaf(J[2], ax, J[3] * ay);
        float p2 = fmaf(J[4], ax, J[5] * ay);
        float p3 = fmaf(J[6], ax, J[7] * ay);
        float mn = fminf(fminf(p0, p1), fminf(p2, p3));
        float mx = fmaxf(fmaxf(p0, p1), fmaxf(p2, p3));
        g = fminf(g, giou1d(I[14], I[15], mn, mx));
    }
    {   // gB axis 0: I corners onto J axis0 vs J self-proj
        float ax = J[8], ay = J[9];
        float p0 = fmaf(I[0], ax, I[1] * ay);
        float p1 = fmaf(I[2], ax, I[3] * ay);
        float p2 = fmaf(I[4], ax, I[5] * ay);
        float p3 = fmaf(I[6], ax, I[7] * ay);
        float mn = fminf(fminf(p0, p1), fminf(p2, p3));
        float mx = fmaxf(fmaxf(p0, p1), fmaxf(p2, p3));
        g = fminf(g, giou1d(mn, mx, J[12], J[13]));
    }
    {   // gB axis 1
        float ax = J[10], ay = J[11];
        float p0 = fmaf(I[0], ax, I[1] * ay);
        float p1 = fmaf(I[2], ax, I[3] * ay);
        float p2 = fmaf(I[4], ax, I[5] * ay);
        float p3 = fmaf(I[6], ax, I[7] * ay);
        float mn = fminf(fminf(p0, p1), fminf(p2, p3));
        float mx = fmaxf(fmaxf(p0, p1), fmaxf(p2, p3));
        g = fminf(g, giou1d(mn, mx, J[14], J[15]));
    }
    return fmaxf(g, 0.0f);
}

// Output is symmetric (giou1d is symmetric in its two intervals =>
// gA[i,j,a] == gB[j,i,a] => g[i,j] == g[j,i]). Compute upper-triangle
// 32x32 tiles only; write both the tile and its transpose.
__global__ __launch_bounds__(256)
void pairwise_kernel(const float* __restrict__ bd, float* __restrict__ out) {
    int bj = blockIdx.x;   // tile col
    int bi = blockIdx.y;   // tile row
    if (bi > bj) return;   // lower-triangle blocks exit immediately

    __shared__ float sI[TILE][16];
    __shared__ float sJ[TILE][16];
    __shared__ float tileT[TILE][TILE + 1];

    int tid = threadIdx.x;
    {   // stage 64 structs (16 floats each): one float4 per thread
        int st = tid >> 2;          // struct 0..63
        int q  = tid & 3;           // float4 slot
        int box = (st < TILE) ? (bi * TILE + st) : (bj * TILE + (st - TILE));
        float4 v = ((const float4*)(bd + (size_t)box * 16))[q];
        float* dstp = (st < TILE) ? &sI[st][0] : &sJ[st - TILE][0];
        ((float4*)dstp)[q] = v;
    }
    __syncthreads();

    int tx = tid & 15;
    int ty = tid >> 4;
    // micro-tile: i_local in {ty, ty+16}, j_local in {tx, tx+16}
    const float* I0 = &sI[ty][0];
    const float* I1 = &sI[ty + 16][0];
    const float* J0 = &sJ[tx][0];
    const float* J1 = &sJ[tx + 16][0];

    int ig0 = bi * TILE + ty, ig1 = ig0 + 16;
    int jg0 = bj * TILE + tx, jg1 = jg0 + 16;

    float v00 = (ig0 == jg0) ? 0.0f : mgiou_pair(I0, J0);
    float v01 = (ig0 == jg1) ? 0.0f : mgiou_pair(I0, J1);
    float v10 = (ig1 == jg0) ? 0.0f : mgiou_pair(I1, J0);
    float v11 = (ig1 == jg1) ? 0.0f : mgiou_pair(I1, J1);

    // direct (upper) tile writes — lanes tx contiguous in j
    out[(size_t)ig0 * NBOX + jg0] = v00;
    out[(size_t)ig0 * NBOX + jg1] = v01;
    out[(size_t)ig1 * NBOX + jg0] = v10;
    out[(size_t)ig1 * NBOX + jg1] = v11;

    // transposed (lower) tile via padded LDS transpose
    tileT[ty][tx]           = v00;
    tileT[ty][tx + 16]      = v01;
    tileT[ty + 16][tx]      = v10;
    tileT[ty + 16][tx + 16] = v11;
    __syncthreads();

    // out[(bj*T + jl)*N + bi*T + il] = tileT[il][jl]
    int ibase = bi * TILE;
    int jbase = bj * TILE;
    #pragma unroll
    for (int dr = 0; dr < 2; ++dr) {
        int jl = ty + dr * 16;
        #pragma unroll
        for (int dc = 0; dc < 2; ++dc) {
            int il = tx + dc * 16;
            out[(size_t)(jbase + jl) * NBOX + (ibase + il)] = tileT[il][jl];
        }
    }
}

extern "C" void kernel_launch(void* const* d_in, const int* in_sizes, int n_in,
                              void* d_out, int out_size, void* d_ws, size_t ws_size,
                              hipStream_t stream) {
    const float* boxes = (const float*)d_in[0];
    float* out = (float*)d_out;
    float* bd = (float*)d_ws;   // 4096 * 16 floats = 256 KB

    precompute_kernel<<<dim3((NBOX + 255) / 256), dim3(256), 0, stream>>>(boxes, bd);

    dim3 grid(NT, NT);
    pairwise_kernel<<<grid, dim3(256), 0, stream>>>(bd, out);
}

// Round 2
// 95.916 us; speedup vs baseline: 1.1125x; 1.1125x over previous
//
#include <hip/hip_runtime.h>
#include <math.h>

#define NBOX 4096
#define TILE 32
#define NT (NBOX / TILE)               // 128
#define NBLK (NT * (NT + 1) / 2)       // 8256 upper-triangle tiles
#define SS 12                          // struct stride in floats (48 B, 16B-aligned, conflict-free)

// Per-box struct (12 floats):
// [0]c0x [1]c0y [2]a0x [3]a0y | [4]a1x [5]a1y [6]smin0 [7]smax0 | [8]len0 [9]smin1 [10]smax1 [11]len1
// c0 = corner 0; a0 = c1-c0; a1 = c3-c0 (a0 ⊥ a1 for a rectangle).
// smin/smax = self-projection interval on own axis; len = |a|^2 = smax - smin.

struct Box {
    float c0x, c0y, a0x, a0y, a1x, a1y;
    float smin0, smax0, len0, smin1, smax1, len1;
};

__device__ __forceinline__ float rcp_fast(float x) {
    return __builtin_amdgcn_rcpf(x);
}

// GIoU-1D for one axis: P's axis (wx,wy) with P's precomputed self interval
// (smin, smax, slen), projecting Q's corners via the Minkowski decomposition:
// corners(Q) = c0 + {0,a0} (+) {0,a1}  =>  min/max separable, len = |da|+|db|.
// Single-rcp form: g = (inter*hull - (hull-uni)*uni) / (uni*hull).
__device__ __forceinline__ float giou_axis(float wx, float wy,
                                           float smin, float smax, float slen,
                                           const Box& Q) {
    float p0 = fmaf(wx, Q.c0x, wy * Q.c0y);
    float da = fmaf(wx, Q.a0x, wy * Q.a0y);
    float db = fmaf(wx, Q.a1x, wy * Q.a1y);
    float mn = p0 + fminf(da, 0.0f) + fminf(db, 0.0f);
    float mx = p0 + fmaxf(da, 0.0f) + fmaxf(db, 0.0f);
    float len2 = fabsf(da) + fabsf(db);          // == mx - mn
    float inter = fmaxf(fminf(smax, mx) - fmaxf(smin, mn), 0.0f);
    float uni  = slen + len2 - inter;
    float hull = fmaxf(smax, mx) - fminf(smin, mn);
    float num  = fmaf(inter, hull, -(hull - uni) * uni);
    return num * rcp_fast(uni * hull);
}

__device__ __forceinline__ float mgiou_pair(const Box& I, const Box& J) {
    float g0 = giou_axis(I.a0x, I.a0y, I.smin0, I.smax0, I.len0, J);
    float g1 = giou_axis(I.a1x, I.a1y, I.smin1, I.smax1, I.len1, J);
    float g2 = giou_axis(J.a0x, J.a0y, J.smin0, J.smax0, J.len0, I);
    float g3 = giou_axis(J.a1x, J.a1y, J.smin1, J.smax1, J.len1, I);
    float g = fminf(fminf(g0, g1), fminf(g2, g3));
    return fmaxf(g, 0.0f);
}

__device__ __forceinline__ Box load_box(const float* __restrict__ p) {
    Box b;
    float4 x = *(const float4*)(p);
    float4 y = *(const float4*)(p + 4);
    float4 z = *(const float4*)(p + 8);
    b.c0x = x.x; b.c0y = x.y; b.a0x = x.z; b.a0y = x.w;
    b.a1x = y.x; b.a1y = y.y; b.smin0 = y.z; b.smax0 = y.w;
    b.len0 = z.x; b.smin1 = z.y; b.smax1 = z.z; b.len1 = z.w;
    return b;
}

// Output is symmetric: giou1d is symmetric in its two intervals, so
// gA[i,j,a] == gB[j,i,a] => g[i,j] == g[j,i]. Compute upper-triangle tiles
// only (linearized grid); mirror via padded LDS transpose.
__global__ __launch_bounds__(256)
void pairwise_kernel(const float* __restrict__ boxes, float* __restrict__ out) {
    // decode (bi, bj), bi <= bj, row-major over the upper triangle
    int k = blockIdx.x;
    int bi = (int)((float)(2 * NT + 1 - sqrtf((float)((2 * NT + 1) * (2 * NT + 1) - 8 * k))) * 0.5f);
    if (bi > 0 && k < bi * NT - bi * (bi - 1) / 2) bi--;
    if (k >= (bi + 1) * NT - (bi + 1) * bi / 2) bi++;
    int bj = bi + (k - (bi * NT - bi * (bi - 1) / 2));

    __shared__ float sm[2 * TILE][SS];          // [0..31] = I boxes, [32..63] = J boxes
    __shared__ float tileT[TILE][TILE + 1];

    int tid = threadIdx.x;
    if (tid < 2 * TILE) {
        // fused precompute: each of 64 threads builds one box struct
        int box = (tid < TILE) ? (bi * TILE + tid) : (bj * TILE + (tid - TILE));
        float cx = boxes[box * 5 + 0];
        float cy = boxes[box * 5 + 1];
        float hw = boxes[box * 5 + 2] * 0.5f;
        float hh = boxes[box * 5 + 3] * 0.5f;
        float ang = boxes[box * 5 + 4];
        float s, c;
        __sincosf(ang, &s, &c);
        float e0x = hw * c, e0y = -hw * s;      // matches reference rot layout
        float e1x = hh * s, e1y =  hh * c;
        float c0x = cx - e0x - e1x, c0y = cy - e0y - e1y;
        float a0x = 2.0f * e0x, a0y = 2.0f * e0y;
        float a1x = 2.0f * e1x, a1y = 2.0f * e1y;
        float l0 = fmaf(a0x, a0x, a0y * a0y);
        float l1 = fmaf(a1x, a1x, a1y * a1y);
        float smin0 = fmaf(a0x, c0x, a0y * c0y);
        float smin1 = fmaf(a1x, c0x, a1y * c0y);
        float* d = &sm[tid][0];
        d[0] = c0x; d[1] = c0y; d[2] = a0x; d[3] = a0y;
        d[4] = a1x; d[5] = a1y; d[6] = smin0; d[7] = smin0 + l0;
        d[8] = l0;  d[9] = smin1; d[10] = smin1 + l1; d[11] = l1;
    }
    __syncthreads();

    int tx = tid & 15;
    int ty = tid >> 4;
    // 2x2 micro-tile: i_local in {ty, ty+16}, j_local in {tx, tx+16}
    Box I0 = load_box(&sm[ty][0]);
    Box I1 = load_box(&sm[ty + 16][0]);
    Box J0 = load_box(&sm[TILE + tx][0]);
    Box J1 = load_box(&sm[TILE + tx + 16][0]);

    int ig0 = bi * TILE + ty, ig1 = ig0 + 16;
    int jg0 = bj * TILE + tx, jg1 = jg0 + 16;

    float v00 = (ig0 == jg0) ? 0.0f : mgiou_pair(I0, J0);
    float v01 = (ig0 == jg1) ? 0.0f : mgiou_pair(I0, J1);
    float v10 = (ig1 == jg0) ? 0.0f : mgiou_pair(I1, J0);
    float v11 = (ig1 == jg1) ? 0.0f : mgiou_pair(I1, J1);

    // upper tile: direct coalesced writes (tx contiguous in j)
    out[(size_t)ig0 * NBOX + jg0] = v00;
    out[(size_t)ig0 * NBOX + jg1] = v01;
    out[(size_t)ig1 * NBOX + jg0] = v10;
    out[(size_t)ig1 * NBOX + jg1] = v11;

    // lower tile: transpose via padded LDS
    tileT[ty][tx]           = v00;
    tileT[ty][tx + 16]      = v01;
    tileT[ty + 16][tx]      = v10;
    tileT[ty + 16][tx + 16] = v11;
    __syncthreads();

    int ibase = bi * TILE;
    int jbase = bj * TILE;
    #pragma unroll
    for (int dr = 0; dr < 2; ++dr) {
        int jl = ty + dr * 16;
        #pragma unroll
        for (int dc = 0; dc < 2; ++dc) {
            int il = tx + dc * 16;
            out[(size_t)(jbase + jl) * NBOX + (ibase + il)] = tileT[il][jl];
        }
    }
}

extern "C" void kernel_launch(void* const* d_in, const int* in_sizes, int n_in,
                              void* d_out, int out_size, void* d_ws, size_t ws_size,
                              hipStream_t stream) {
    const float* boxes = (const float*)d_in[0];
    float* out = (float*)d_out;
    pairwise_kernel<<<dim3(NBLK), dim3(256), 0, stream>>>(boxes, out);
}

// Round 3
// 88.468 us; speedup vs baseline: 1.2061x; 1.0842x over previous
//
#include <hip/hip_runtime.h>
#include <math.h>

#define NBOX 4096
#define TILE 32
#define NT (NBOX / TILE)               // 128
#define NBLK (NT * (NT + 1) / 2)       // 8256 upper-triangle tiles
#define SS 12                          // struct stride in floats (48 B; 12*tx%32 has period 8 -> only 2-way LDS aliasing = free)

// Per-box struct (12 floats):
// [0]c0x [1]c0y [2]a0x [3]a0y | [4]a1x [5]a1y [6]smin0 [7]smax0 | [8]len0 [9]smin1 [10]smax1 [11]len1
// c0 = corner 0; a0 = c1-c0; a1 = c3-c0; smin/smax = self-proj interval; len = |a|^2.

struct Box {
    float c0x, c0y, a0x, a0y, a1x, a1y;
    float smin0, smax0, len0, smin1, smax1, len1;
};

__device__ __forceinline__ float rcp_fast(float x) {
    return __builtin_amdgcn_rcpf(x);
}

// giou1d algebraically collapses: with r = min(mx1,mx2)-max(mn1,mn2) (signed)
// and L = len1+len2, both branches of inter/uni - (hull-uni)/hull reduce to
//   g = r / (L - r),   L - r = hull >= len2 > 0 always.
// Q's projection interval onto axis w via Minkowski decomposition
// (corners = c0 (+) {0,a0} (+) {0,a1}): separable min/max, length |da|+|db|.
__device__ __forceinline__ float giou_axis(float wx, float wy,
                                           float smin, float smax, float slen,
                                           const Box& Q) {
    float p0 = fmaf(wx, Q.c0x, wy * Q.c0y);
    float da = fmaf(wx, Q.a0x, wy * Q.a0y);
    float db = fmaf(wx, Q.a1x, wy * Q.a1y);
    float mn = p0 + fminf(da, 0.0f) + fminf(db, 0.0f);
    float len2 = fabsf(da) + fabsf(db);          // free abs modifiers
    float mx = mn + len2;
    float r = fminf(smax, mx) - fmaxf(smin, mn);
    float L = slen + len2;
    return r * rcp_fast(L - r);
}

__device__ __forceinline__ float mgiou_pair(const Box& I, const Box& J) {
    float g0 = giou_axis(I.a0x, I.a0y, I.smin0, I.smax0, I.len0, J);
    float g1 = giou_axis(I.a1x, I.a1y, I.smin1, I.smax1, I.len1, J);
    float g2 = giou_axis(J.a0x, J.a0y, J.smin0, J.smax0, J.len0, I);
    float g3 = giou_axis(J.a1x, J.a1y, J.smin1, J.smax1, J.len1, I);
    float g = fminf(fminf(g0, g1), fminf(g2, g3));
    return fmaxf(g, 0.0f);
}

__device__ __forceinline__ Box load_box(const float* __restrict__ p) {
    Box b;
    float4 x = *(const float4*)(p);
    float4 y = *(const float4*)(p + 4);
    float4 z = *(const float4*)(p + 8);
    b.c0x = x.x; b.c0y = x.y; b.a0x = x.z; b.a0y = x.w;
    b.a1x = y.x; b.a1y = y.y; b.smin0 = y.z; b.smax0 = y.w;
    b.len0 = z.x; b.smin1 = z.y; b.smax1 = z.z; b.len1 = z.w;
    return b;
}

// Output is symmetric (giou1d symmetric in its two intervals => g[i,j]==g[j,i]).
// Upper-triangle tiles only; mirror via padded LDS transpose.
__global__ __launch_bounds__(256)
void pairwise_kernel(const float* __restrict__ boxes, float* __restrict__ out) {
    // decode (bi, bj), bi <= bj, row-major over the upper triangle
    int k = blockIdx.x;
    int bi = (int)((float)(2 * NT + 1 - sqrtf((float)((2 * NT + 1) * (2 * NT + 1) - 8 * k))) * 0.5f);
    if (bi > 0 && k < bi * NT - bi * (bi - 1) / 2) bi--;
    if (k >= (bi + 1) * NT - (bi + 1) * bi / 2) bi++;
    int bj = bi + (k - (bi * NT - bi * (bi - 1) / 2));

    __shared__ float sm[2 * TILE][SS];          // [0..31] = I boxes, [32..63] = J boxes
    __shared__ float tileT[TILE][TILE + 1];

    int tid = threadIdx.x;
    if (tid < 2 * TILE) {
        // fused precompute: each of 64 threads builds one box struct
        int box = (tid < TILE) ? (bi * TILE + tid) : (bj * TILE + (tid - TILE));
        float cx = boxes[box * 5 + 0];
        float cy = boxes[box * 5 + 1];
        float hw = boxes[box * 5 + 2] * 0.5f;
        float hh = boxes[box * 5 + 3] * 0.5f;
        float ang = boxes[box * 5 + 4];
        float s, c;
        __sincosf(ang, &s, &c);
        float e0x = hw * c, e0y = -hw * s;      // matches reference rot layout
        float e1x = hh * s, e1y =  hh * c;
        float c0x = cx - e0x - e1x, c0y = cy - e0y - e1y;
        float a0x = 2.0f * e0x, a0y = 2.0f * e0y;
        float a1x = 2.0f * e1x, a1y = 2.0f * e1y;
        float l0 = fmaf(a0x, a0x, a0y * a0y);
        float l1 = fmaf(a1x, a1x, a1y * a1y);
        float smin0 = fmaf(a0x, c0x, a0y * c0y);
        float smin1 = fmaf(a1x, c0x, a1y * c0y);
        float* d = &sm[tid][0];
        d[0] = c0x; d[1] = c0y; d[2] = a0x; d[3] = a0y;
        d[4] = a1x; d[5] = a1y; d[6] = smin0; d[7] = smin0 + l0;
        d[8] = l0;  d[9] = smin1; d[10] = smin1 + l1; d[11] = l1;
    }
    __syncthreads();

    int tx = tid & 15;
    int ty = tid >> 4;
    // 2x2 micro-tile: i_local in {ty, ty+16}, j_local in {tx, tx+16}
    Box I0 = load_box(&sm[ty][0]);
    Box I1 = load_box(&sm[ty + 16][0]);
    Box J0 = load_box(&sm[TILE + tx][0]);
    Box J1 = load_box(&sm[TILE + tx + 16][0]);

    int ig0 = bi * TILE + ty, ig1 = ig0 + 16;
    int jg0 = bj * TILE + tx, jg1 = jg0 + 16;

    float v00 = (ig0 == jg0) ? 0.0f : mgiou_pair(I0, J0);
    float v01 = (ig0 == jg1) ? 0.0f : mgiou_pair(I0, J1);
    float v10 = (ig1 == jg0) ? 0.0f : mgiou_pair(I1, J0);
    float v11 = (ig1 == jg1) ? 0.0f : mgiou_pair(I1, J1);

    // upper tile: direct coalesced writes (tx contiguous in j)
    out[(size_t)ig0 * NBOX + jg0] = v00;
    out[(size_t)ig0 * NBOX + jg1] = v01;
    out[(size_t)ig1 * NBOX + jg0] = v10;
    out[(size_t)ig1 * NBOX + jg1] = v11;

    // lower tile: transpose via padded LDS
    tileT[ty][tx]           = v00;
    tileT[ty][tx + 16]      = v01;
    tileT[ty + 16][tx]      = v10;
    tileT[ty + 16][tx + 16] = v11;
    __syncthreads();

    int ibase = bi * TILE;
    int jbase = bj * TILE;
    #pragma unroll
    for (int dr = 0; dr < 2; ++dr) {
        int jl = ty + dr * 16;
        #pragma unroll
        for (int dc = 0; dc < 2; ++dc) {
            int il = tx + dc * 16;
            out[(size_t)(jbase + jl) * NBOX + (ibase + il)] = tileT[il][jl];
        }
    }
}

extern "C" void kernel_launch(void* const* d_in, const int* in_sizes, int n_in,
                              void* d_out, int out_size, void* d_ws, size_t ws_size,
                              hipStream_t stream) {
    const float* boxes = (const float*)d_in[0];
    float* out = (float*)d_out;
    pairwise_kernel<<<dim3(NBLK), dim3(256), 0, stream>>>(boxes, out);
}

// Round 5
// 82.111 us; speedup vs baseline: 1.2995x; 1.0774x over previous
//
#include <hip/hip_runtime.h>
#include <math.h>

#define NBOX 4096
#define TILE 32
#define NT (NBOX / TILE)               // 128
#define NBLK (NT * (NT + 1) / 2)       // 8256 upper-triangle tiles
#define SS 12                          // struct stride in floats (48 B, 16B-aligned)
#define JBASE (TILE * SS)              // J region starts after 32 I-structs

// Per-box struct (10 floats used, stride 12):
// [0]cx [1]cy [2]a0x [3]a0y | [4]a1x [5]a1y [6]sc0 [7]sc1 | [8]l0 [9]l1
// a0/a1 = full edge vectors (a0 ⊥ a1); sc = a·center (self-proj center);
// l = |a|^2 (self-proj full length). Projections onto unnormalized axes —
// the giou ratio is scale-invariant, matching the reference exactly.

struct Box {
    float cx, cy, a0x, a0y, a1x, a1y, sc0, sc1, l0, l1;
};

__device__ __forceinline__ float rcp_fast(float x) {
    return __builtin_amdgcn_rcpf(x);
}

// One axis: self interval (center folded into D, full length H1) vs other
// interval (full length H2, center offset D).
// Exact identities:  overlap r = min(H1, H2, (H1+H2)/2 - |D|)   (signed)
//                    giou1d  g = r / (H1 + H2 - r)              (denom > 0)
__device__ __forceinline__ float giou_axis1(float H1, float H2, float D) {
    float S = H1 + H2;
    float u = fmaf(0.5f, S, -fabsf(D));
    float r = fminf(fminf(H1, H2), u);   // -> v_min3_f32
    return r * rcp_fast(S - r);
}

// The 4 cross dot-products d_ab = aA_I . aB_J are shared by all 4 axes.
__device__ __forceinline__ float mgiou_pair(const Box& I, const Box& J) {
    float d00 = fmaf(I.a0x, J.a0x, I.a0y * J.a0y);
    float d01 = fmaf(I.a0x, J.a1x, I.a0y * J.a1y);
    float d10 = fmaf(I.a1x, J.a0x, I.a1y * J.a0y);
    float d11 = fmaf(I.a1x, J.a1x, I.a1y * J.a1y);
    // center offsets D = w . c_other - sc_self (two fmas each)
    float DI0 = fmaf(I.a0x, J.cx, fmaf(I.a0y, J.cy, -I.sc0));
    float DI1 = fmaf(I.a1x, J.cx, fmaf(I.a1y, J.cy, -I.sc1));
    float DJ0 = fmaf(J.a0x, I.cx, fmaf(J.a0y, I.cy, -J.sc0));
    float DJ1 = fmaf(J.a1x, I.cx, fmaf(J.a1y, I.cy, -J.sc1));
    // projected full lengths (abs modifiers are free on the adds)
    float HI0 = fabsf(d00) + fabsf(d01);
    float HI1 = fabsf(d10) + fabsf(d11);
    float HJ0 = fabsf(d00) + fabsf(d10);
    float HJ1 = fabsf(d01) + fabsf(d11);
    float g0 = giou_axis1(I.l0, HI0, DI0);
    float g1 = giou_axis1(I.l1, HI1, DI1);
    float g2 = giou_axis1(J.l0, HJ0, DJ0);
    float g3 = giou_axis1(J.l1, HJ1, DJ1);
    float g = fminf(fminf(g0, g1), fminf(g2, g3));
    return fmaxf(g, 0.0f);
}

// CUMULATIVE swizzle: +4 floats per 8-struct group (monotone -> no overlap,
// unlike the round-4 alternating version which collided at struct 15/16).
// Even-struct b128 reads then start at cosets {0,24,16,8,4,28,20,12} ->
// all 8 bank-cosets, 2-way aliasing only (free). Same for odd structs.
// j_offset(2tx+1) == j_offset(2tx)+SS since bit0 doesn't affect j>>3.
__device__ __forceinline__ int j_offset(int j) {
    return JBASE + j * SS + (j >> 3) * 4;
}

__device__ __forceinline__ Box load_box(const float* p) {
    Box b;
    float4 x = *(const float4*)(p);
    float4 y = *(const float4*)(p + 4);
    float2 z = *(const float2*)(p + 8);
    b.cx = x.x;  b.cy = x.y;  b.a0x = x.z; b.a0y = x.w;
    b.a1x = y.x; b.a1y = y.y; b.sc0 = y.z; b.sc1 = y.w;
    b.l0 = z.x;  b.l1 = z.y;
    return b;
}

// Output is symmetric (giou1d symmetric in its two intervals => g[i,j]==g[j,i]).
// Upper-triangle tiles only; mirror via padded LDS transpose.
__global__ __launch_bounds__(256)
void pairwise_kernel(const float* __restrict__ boxes, float* __restrict__ out) {
    // decode (bi, bj), bi <= bj, row-major over the upper triangle
    int k = blockIdx.x;
    int bi = (int)((float)(2 * NT + 1 - sqrtf((float)((2 * NT + 1) * (2 * NT + 1) - 8 * k))) * 0.5f);
    if (bi > 0 && k < bi * NT - bi * (bi - 1) / 2) bi--;
    if (k >= (bi + 1) * NT - (bi + 1) * bi / 2) bi++;
    int bj = bi + (k - (bi * NT - bi * (bi - 1) / 2));

    __shared__ float sm[JBASE + TILE * SS + 16];  // I structs + swizzled J structs
    __shared__ float tileT[TILE][TILE + 1];

    int tid = threadIdx.x;
    if (tid < 2 * TILE) {
        // fused precompute: each of 64 threads builds one box struct
        int loc = (tid < TILE) ? tid : (tid - TILE);
        int box = (tid < TILE) ? (bi * TILE + loc) : (bj * TILE + loc);
        float cx = boxes[box * 5 + 0];
        float cy = boxes[box * 5 + 1];
        float w  = boxes[box * 5 + 2];
        float h  = boxes[box * 5 + 3];
        float ang = boxes[box * 5 + 4];
        float s, c;
        __sincosf(ang, &s, &c);
        float a0x = w * c, a0y = -w * s;    // full edge vectors (match ref rot)
        float a1x = h * s, a1y =  h * c;
        float sc0 = fmaf(a0x, cx, a0y * cy);
        float sc1 = fmaf(a1x, cx, a1y * cy);
        float* d = &sm[(tid < TILE) ? (loc * SS) : j_offset(loc)];
        ((float4*)d)[0] = make_float4(cx, cy, a0x, a0y);
        ((float4*)d)[1] = make_float4(a1x, a1y, sc0, sc1);
        ((float2*)d)[4] = make_float2(w * w, h * h);
    }
    __syncthreads();

    int tx = tid & 15;          // j-pair: j = 2tx, 2tx+1
    int ty = tid >> 4;          // i: ty, ty+16
    Box I0 = load_box(&sm[ty * SS]);
    Box I1 = load_box(&sm[(ty + 16) * SS]);
    const float* jp = &sm[j_offset(2 * tx)];
    Box J0 = load_box(jp);
    Box J1 = load_box(jp + SS);

    int ibase = bi * TILE, jbase = bj * TILE;
    int ig0 = ibase + ty, ig1 = ig0 + 16;
    int jg0 = jbase + 2 * tx, jg1 = jg0 + 1;

    float v00 = (ig0 == jg0) ? 0.0f : mgiou_pair(I0, J0);
    float v01 = (ig0 == jg1) ? 0.0f : mgiou_pair(I0, J1);
    float v10 = (ig1 == jg0) ? 0.0f : mgiou_pair(I1, J0);
    float v11 = (ig1 == jg1) ? 0.0f : mgiou_pair(I1, J1);

    // upper tile: float2 coalesced (16 lanes x 8 B = 128 B per ty-row)
    *(float2*)&out[(size_t)ig0 * NBOX + jg0] = make_float2(v00, v01);
    *(float2*)&out[(size_t)ig1 * NBOX + jg0] = make_float2(v10, v11);

    // lower tile: transpose via padded LDS
    tileT[ty][2 * tx]          = v00;
    tileT[ty][2 * tx + 1]      = v01;
    tileT[ty + 16][2 * tx]     = v10;
    tileT[ty + 16][2 * tx + 1] = v11;
    __syncthreads();

    #pragma unroll
    for (int dr = 0; dr < 2; ++dr) {
        int jl = ty + dr * 16;
        float2 o = make_float2(tileT[2 * tx][jl], tileT[2 * tx + 1][jl]);
        *(float2*)&out[(size_t)(jbase + jl) * NBOX + ibase + 2 * tx] = o;
    }
}

extern "C" void kernel_launch(void* const* d_in, const int* in_sizes, int n_in,
                              void* d_out, int out_size, void* d_ws, size_t ws_size,
                              hipStream_t stream) {
    const float* boxes = (const float*)d_in[0];
    float* out = (float*)d_out;
    pairwise_kernel<<<dim3(NBLK), dim3(256), 0, stream>>>(boxes, out);
}

// Round 7
// 81.990 us; speedup vs baseline: 1.3014x; 1.0015x over previous
//
#include <hip/hip_runtime.h>
#include <math.h>

#define NBOX 4096
#define TILE 64
#define NT (NBOX / TILE)               // 64
#define NBLK (NT * (NT + 1) / 2)       // 2080 upper-triangle tiles
#define SS 12                          // struct stride in floats (48 B, 16B-aligned)
#define JBASE (TILE * SS)              // J region starts after 64 I-structs

typedef float vfloat4 __attribute__((ext_vector_type(4)));  // clang vector: valid for __builtin_nontemporal_store

// Per-box struct (10 floats used, stride 12):
// [0]cx [1]cy [2]a0x [3]a0y | [4]a1x [5]a1y [6]sc0 [7]sc1 | [8]l0 [9]l1
// a0/a1 = full edge vectors (a0 ⊥ a1); sc = a·center; l = |a|^2.
// Projections onto unnormalized axes — giou ratio is scale-invariant.

struct Box {
    float cx, cy, a0x, a0y, a1x, a1y, sc0, sc1, l0, l1;
};

__device__ __forceinline__ float rcp_fast(float x) {
    return __builtin_amdgcn_rcpf(x);
}

// Exact identities:  overlap r = min(H1, H2, (H1+H2)/2 - |D|)   (signed)
//                    giou1d  g = r / (H1 + H2 - r)              (denom > 0)
__device__ __forceinline__ float giou_axis1(float H1, float H2, float D) {
    float S = H1 + H2;
    float u = fmaf(0.5f, S, -fabsf(D));
    float r = fminf(fminf(H1, H2), u);   // -> v_min3_f32
    return r * rcp_fast(S - r);
}

// The 4 cross dot-products d_ab = aA_I . aB_J are shared by all 4 axes.
__device__ __forceinline__ float mgiou_pair(const Box& I, const Box& J) {
    float d00 = fmaf(I.a0x, J.a0x, I.a0y * J.a0y);
    float d01 = fmaf(I.a0x, J.a1x, I.a0y * J.a1y);
    float d10 = fmaf(I.a1x, J.a0x, I.a1y * J.a0y);
    float d11 = fmaf(I.a1x, J.a1x, I.a1y * J.a1y);
    float DI0 = fmaf(I.a0x, J.cx, fmaf(I.a0y, J.cy, -I.sc0));
    float DI1 = fmaf(I.a1x, J.cx, fmaf(I.a1y, J.cy, -I.sc1));
    float DJ0 = fmaf(J.a0x, I.cx, fmaf(J.a0y, I.cy, -J.sc0));
    float DJ1 = fmaf(J.a1x, I.cx, fmaf(J.a1y, I.cy, -J.sc1));
    float HI0 = fabsf(d00) + fabsf(d01);
    float HI1 = fabsf(d10) + fabsf(d11);
    float HJ0 = fabsf(d00) + fabsf(d10);
    float HJ1 = fabsf(d01) + fabsf(d11);
    float g0 = giou_axis1(I.l0, HI0, DI0);
    float g1 = giou_axis1(I.l1, HI1, DI1);
    float g2 = giou_axis1(J.l0, HJ0, DJ0);
    float g3 = giou_axis1(J.l1, HJ1, DJ1);
    float g = fminf(fminf(g0, g1), fminf(g2, g3));
    return fmaxf(g, 0.0f);
}

// Cumulative swizzle: +4 floats per 8-struct group (monotone, no overlap).
// b128 start cosets cover all 8 4-aligned cosets twice -> 2-way = free.
// Structs 4tx..4tx+3 sit in one octet (4tx mod 8 in {0,4}), so jp+m*SS valid.
__device__ __forceinline__ int j_offset(int j) {
    return JBASE + j * SS + (j >> 3) * 4;
}

__device__ __forceinline__ Box load_box(const float* p) {
    Box b;
    float4 x = *(const float4*)(p);
    float4 y = *(const float4*)(p + 4);
    float2 z = *(const float2*)(p + 8);
    b.cx = x.x;  b.cy = x.y;  b.a0x = x.z; b.a0y = x.w;
    b.a1x = y.x; b.a1y = y.y; b.sc0 = y.z; b.sc1 = y.w;
    b.l0 = z.x;  b.l1 = z.y;
    return b;
}

// Output symmetric => upper-triangle 64x64 tiles; mirror via padded LDS transpose.
// 4x4 micro-tile per thread: i in {ty+16k}, j in {4tx..4tx+3} (float4 stores).
__global__ __launch_bounds__(256)
void pairwise_kernel(const float* __restrict__ boxes, float* __restrict__ out) {
    // decode (bi, bj), bi <= bj, row-major over the upper triangle
    int k = blockIdx.x;
    int bi = (int)((float)(2 * NT + 1 - sqrtf((float)((2 * NT + 1) * (2 * NT + 1) - 8 * k))) * 0.5f);
    if (bi > 0 && k < bi * NT - bi * (bi - 1) / 2) bi--;
    if (k >= (bi + 1) * NT - (bi + 1) * bi / 2) bi++;
    int bj = bi + (k - (bi * NT - bi * (bi - 1) / 2));

    __shared__ float sm[JBASE + TILE * SS + ((TILE - 1) >> 3) * 4 + 8];
    __shared__ float tileT[TILE][TILE + 1];

    int tid = threadIdx.x;
    if (tid < 2 * TILE) {
        // fused precompute: 128 threads each build one box struct
        int loc = tid & (TILE - 1);
        int box = ((tid < TILE) ? bi : bj) * TILE + loc;
        float cx = boxes[box * 5 + 0];
        float cy = boxes[box * 5 + 1];
        float w  = boxes[box * 5 + 2];
        float h  = boxes[box * 5 + 3];
        float ang = boxes[box * 5 + 4];
        float s, c;
        __sincosf(ang, &s, &c);
        float a0x = w * c, a0y = -w * s;    // full edge vectors (match ref rot)
        float a1x = h * s, a1y =  h * c;
        float sc0 = fmaf(a0x, cx, a0y * cy);
        float sc1 = fmaf(a1x, cx, a1y * cy);
        float* d = &sm[(tid < TILE) ? (loc * SS) : j_offset(loc)];
        ((float4*)d)[0] = make_float4(cx, cy, a0x, a0y);
        ((float4*)d)[1] = make_float4(a1x, a1y, sc0, sc1);
        ((float2*)d)[4] = make_float2(w * w, h * h);
    }
    __syncthreads();

    int tx = tid & 15;          // j quad: 4tx .. 4tx+3
    int ty = tid >> 4;          // i rows: ty + 16k, k=0..3
    Box I[4], J[4];
    #pragma unroll
    for (int kk = 0; kk < 4; ++kk) I[kk] = load_box(&sm[(ty + 16 * kk) * SS]);
    const float* jp = &sm[j_offset(4 * tx)];
    #pragma unroll
    for (int m = 0; m < 4; ++m) J[m] = load_box(jp + m * SS);

    int ibase = bi * TILE, jbase = bj * TILE;
    float v[4][4];
    #pragma unroll
    for (int kk = 0; kk < 4; ++kk) {
        int ig = ibase + ty + 16 * kk;
        #pragma unroll
        for (int m = 0; m < 4; ++m) {
            int jg = jbase + 4 * tx + m;
            v[kk][m] = (ig == jg) ? 0.0f : mgiou_pair(I[kk], J[m]);
        }
    }

    // upper tile: float4 nontemporal stores (16 lanes x 16 B = 256 B per row)
    #pragma unroll
    for (int kk = 0; kk < 4; ++kk) {
        int ig = ibase + ty + 16 * kk;
        vfloat4 o = {v[kk][0], v[kk][1], v[kk][2], v[kk][3]};
        __builtin_nontemporal_store(o, (vfloat4*)&out[(size_t)ig * NBOX + jbase + 4 * tx]);
    }

    // lower tile: transpose via padded LDS (all patterns 2-way banked = free)
    #pragma unroll
    for (int kk = 0; kk < 4; ++kk)
        #pragma unroll
        for (int m = 0; m < 4; ++m)
            tileT[ty + 16 * kk][4 * tx + m] = v[kk][m];
    __syncthreads();

    #pragma unroll
    for (int kk = 0; kk < 4; ++kk) {
        int jl = ty + 16 * kk;
        vfloat4 o = {tileT[4 * tx + 0][jl], tileT[4 * tx + 1][jl],
                     tileT[4 * tx + 2][jl], tileT[4 * tx + 3][jl]};
        __builtin_nontemporal_store(o, (vfloat4*)&out[(size_t)(jbase + jl) * NBOX + ibase + 4 * tx]);
    }
}

extern "C" void kernel_launch(void* const* d_in, const int* in_sizes, int n_in,
                              void* d_out, int out_size, void* d_ws, size_t ws_size,
                              hipStream_t stream) {
    const float* boxes = (const float*)d_in[0];
    float* out = (float*)d_out;
    pairwise_kernel<<<dim3(NBLK), dim3(256), 0, stream>>>(boxes, out);
}